// Round 5
// baseline (108.642 us; speedup 1.0000x reference)
//
#include <hip/hip_runtime.h>
#include <cmath>

#define NN 8192
#define MM 64
#define OFF 1e-6f
#define CEPS 1e-8f

typedef float float4n __attribute__((ext_vector_type(4)));

// ---------------- Kernel 1: ev = exp(beta*K) + per-batch Z accumulation ------
// grid = B*32 blocks, 256 threads. Each block: 256 rows of one batch.
// 8-lane group per row, 8 floats/lane (two float4 halves of the 64-f row).
__global__ __launch_bounds__(256) void ntm_scores(
    const float* __restrict__ memory, const float* __restrict__ k_t,
    const float* __restrict__ beta_t, float* __restrict__ out,
    float* __restrict__ zacc)
{
    const int b = blockIdx.x >> 5;                     // /32
    const int rowBase = (blockIdx.x & 31) * 256;
    const int tid = threadIdx.x;
    const int lane8 = tid & 7;
    const int group = tid >> 3;                        // 0..31

    // k (+OFF, kept: free) — lane holds elems [lane8*4,+4) and [32+lane8*4,+4)
    float4 kd0 = *(const float4*)(k_t + b * MM + lane8 * 4);
    float4 kd1 = *(const float4*)(k_t + b * MM + 32 + lane8 * 4);
    kd0.x += OFF; kd0.y += OFF; kd0.z += OFF; kd0.w += OFF;
    kd1.x += OFF; kd1.y += OFF; kd1.z += OFF; kd1.w += OFF;
    float bn = kd0.x*kd0.x + kd0.y*kd0.y + kd0.z*kd0.z + kd0.w*kd0.w
             + kd1.x*kd1.x + kd1.y*kd1.y + kd1.z*kd1.z + kd1.w*kd1.w;
    #pragma unroll
    for (int m = 1; m <= 4; m <<= 1) bn += __shfl_xor(bn, m, 64);
    const float bden = fmaxf(sqrtf(bn), CEPS);
    const float rbeta = beta_t[b] / bden;              // beta / ||b||
    const float* memb = memory + (size_t)b * NN * MM;

    float zpart = 0.f;
    #pragma unroll
    for (int it = 0; it < 8; ++it) {
        const int row = rowBase + it * 32 + group;
        const float4n* rowp = (const float4n*)(memb + (size_t)row * MM);
        const float4n a0 = __builtin_nontemporal_load(rowp + lane8);
        const float4n a1 = __builtin_nontemporal_load(rowp + 8 + lane8);
        // drop +OFF on memory: ~1e-6 relative effect, far under threshold
        float num = a0.x*kd0.x + a0.y*kd0.y + a0.z*kd0.z + a0.w*kd0.w
                  + a1.x*kd1.x + a1.y*kd1.y + a1.z*kd1.z + a1.w*kd1.w;
        float nrm = a0.x*a0.x + a0.y*a0.y + a0.z*a0.z + a0.w*a0.w
                  + a1.x*a1.x + a1.y*a1.y + a1.z*a1.z + a1.w*a1.w;
        #pragma unroll
        for (int m = 1; m <= 4; m <<= 1) {
            num += __shfl_xor(num, m, 64);
            nrm += __shfl_xor(nrm, m, 64);
        }
        const float betaK = rbeta * num * __frsqrt_rn(fmaxf(nrm, 1e-16f));
        const float ev = __expf(betaK);                // betaK in [-5,5]: safe
        zpart += ev;
        if (lane8 == 0) out[(size_t)b * NN + row] = ev;
    }
    // sum zpart across the 8 groups of this wave (each group's 8 lanes
    // hold identical zpart; masks 8,16,32 combine one lane per group)
    #pragma unroll
    for (int m = 8; m <= 32; m <<= 1) zpart += __shfl_xor(zpart, m, 64);
    if ((tid & 63) == 0) atomicAdd(&zacc[b], zpart);
}

// ---------------- Kernel 2: blend + conv + pow + sum -------------------------
__device__ __forceinline__ float blockReduceSum(float x, float* red) {
    #pragma unroll
    for (int m = 32; m >= 1; m >>= 1) x += __shfl_xor(x, m, 64);
    const int wave = threadIdx.x >> 6;
    const int lane = threadIdx.x & 63;
    if (lane == 0) red[wave] = x;
    __syncthreads();
    if (threadIdx.x < 64) {
        float y = (threadIdx.x < 16) ? red[threadIdx.x] : 0.f;
        #pragma unroll
        for (int m = 8; m >= 1; m >>= 1) y += __shfl_xor(y, m, 64);
        if (threadIdx.x == 0) red[0] = y;
    }
    __syncthreads();
    return red[0];
}

__global__ __launch_bounds__(1024) void ntm_finalize(
    const float* __restrict__ g_t, const float* __restrict__ s_t,
    const float* __restrict__ gamma_t, const float* __restrict__ w_prev,
    const float* __restrict__ zacc, float* __restrict__ io)
{
    __shared__ float sh[NN];               // 32 KB: w_g row
    __shared__ float red[16];
    const int b = blockIdx.x;
    const int tid = threadIdx.x;
    const size_t base = (size_t)b * NN;

    const float Z = zacc[b];
    const float g = g_t[b];
    const float gamma = gamma_t[b];
    const float s0 = s_t[b * 3 + 0], s1 = s_t[b * 3 + 1], s2 = s_t[b * 3 + 2];
    const float gz = g / Z;
    const float omg = 1.f - g;

    #pragma unroll
    for (int k = 0; k < 8; ++k) {
        const int i = tid + k * 1024;
        sh[i] = io[base + i] * gz + omg * w_prev[base + i];   // w_g (>0)
    }
    __syncthreads();

    float wsum = 0.f;
    #pragma unroll
    for (int k = 0; k < 8; ++k) {
        const int i = tid + k * 1024;
        const float wt = s0 * sh[(i + NN - 1) & (NN - 1)]
                       + s1 * sh[i]
                       + s2 * sh[(i + 1) & (NN - 1)];
        wsum += exp2f(gamma * __log2f(wt));            // wt > 0 always
    }
    const float total = blockReduceSum(wsum, red) + OFF;

    #pragma unroll
    for (int k = 0; k < 8; ++k) io[base + tid + k * 1024] = total;
}

// ---------------- launch -----------------------------------------------------
extern "C" void kernel_launch(void* const* d_in, const int* in_sizes, int n_in,
                              void* d_out, int out_size, void* d_ws, size_t ws_size,
                              hipStream_t stream) {
    const float* memory = (const float*)d_in[0];
    const float* k_t    = (const float*)d_in[1];
    const float* beta_t = (const float*)d_in[2];
    const float* g_t    = (const float*)d_in[3];
    const float* s_t    = (const float*)d_in[4];
    const float* gamma_t= (const float*)d_in[5];
    const float* w_prev = (const float*)d_in[6];
    float* out = (float*)d_out;
    float* zacc = (float*)d_ws;            // B floats of scratch
    const int B = in_sizes[2];             // beta_t element count = 128

    (void)hipMemsetAsync(zacc, 0, B * sizeof(float), stream);
    ntm_scores<<<B * 32, 256, 0, stream>>>(memory, k_t, beta_t, out, zacc);
    ntm_finalize<<<B, 1024, 0, stream>>>(g_t, s_t, gamma_t, w_prev, zacc, out);
}

// Round 6
// 51.964 us; speedup vs baseline: 2.0907x; 2.0907x over previous
//
#include <hip/hip_runtime.h>
#include <cmath>

#define NN 8192
#define MM 64
#define OFF 1e-6f
#define CEPS 1e-8f

// ---------------- Kernel 1: ev = exp(beta*K) + per-wave partial Z ------------
// grid = B*32 blocks, 256 threads. Each block: 256 rows of one batch.
// 8-lane group per row, 8 floats/lane (two float4 halves of the 64-f row).
// Memory loop identical to the measured-51.8us R3 kernel (plain loads, unroll 2).
__global__ __launch_bounds__(256) void ntm_scores(
    const float* __restrict__ memory, const float* __restrict__ k_t,
    const float* __restrict__ beta_t, float* __restrict__ out,
    float* __restrict__ zpartial)
{
    const int b = blockIdx.x >> 5;                     // /32
    const int blk = blockIdx.x & 31;
    const int rowBase = blk * 256;
    const int tid = threadIdx.x;
    const int lane8 = tid & 7;
    const int group = tid >> 3;                        // 0..31

    float4 kd0 = *(const float4*)(k_t + b * MM + lane8 * 4);
    float4 kd1 = *(const float4*)(k_t + b * MM + 32 + lane8 * 4);
    kd0.x += OFF; kd0.y += OFF; kd0.z += OFF; kd0.w += OFF;
    kd1.x += OFF; kd1.y += OFF; kd1.z += OFF; kd1.w += OFF;
    float bn = kd0.x*kd0.x + kd0.y*kd0.y + kd0.z*kd0.z + kd0.w*kd0.w
             + kd1.x*kd1.x + kd1.y*kd1.y + kd1.z*kd1.z + kd1.w*kd1.w;
    #pragma unroll
    for (int m = 1; m <= 4; m <<= 1) bn += __shfl_xor(bn, m, 64);
    const float bden = fmaxf(sqrtf(bn), CEPS);
    const float rbeta = beta_t[b] / bden;              // beta / ||b||
    const float* memb = memory + (size_t)b * NN * MM;

    float zpart = 0.f;
    #pragma unroll 2
    for (int it = 0; it < 8; ++it) {
        const int row = rowBase + it * 32 + group;
        const float* rowp = memb + (size_t)row * MM;
        float4 a0 = *(const float4*)(rowp + lane8 * 4);
        float4 a1 = *(const float4*)(rowp + 32 + lane8 * 4);
        // +OFF on memory dropped: ~1e-6 relative effect, far under threshold
        float num = a0.x*kd0.x + a0.y*kd0.y + a0.z*kd0.z + a0.w*kd0.w
                  + a1.x*kd1.x + a1.y*kd1.y + a1.z*kd1.z + a1.w*kd1.w;
        float nrm = a0.x*a0.x + a0.y*a0.y + a0.z*a0.z + a0.w*a0.w
                  + a1.x*a1.x + a1.y*a1.y + a1.z*a1.z + a1.w*a1.w;
        #pragma unroll
        for (int m = 1; m <= 4; m <<= 1) {
            num += __shfl_xor(num, m, 64);
            nrm += __shfl_xor(nrm, m, 64);
        }
        const float betaK = rbeta * num / fmaxf(sqrtf(nrm), CEPS);
        const float ev = __expf(betaK);                // betaK in [-5,5]: safe
        zpart += ev;
        if (lane8 == 0) out[(size_t)b * NN + row] = ev;
    }
    // combine the 8 groups of this wave (lanes within a group hold equal zpart)
    #pragma unroll
    for (int m = 8; m <= 32; m <<= 1) zpart += __shfl_xor(zpart, m, 64);
    if ((tid & 63) == 0)
        zpartial[b * 128 + blk * 4 + (tid >> 6)] = zpart;   // plain store
}

// ---------------- Kernel 2: Z-sum + blend + conv + pow + sum -----------------
__device__ __forceinline__ float blockReduceSum(float x, float* red) {
    #pragma unroll
    for (int m = 32; m >= 1; m >>= 1) x += __shfl_xor(x, m, 64);
    const int wave = threadIdx.x >> 6;
    const int lane = threadIdx.x & 63;
    __syncthreads();                       // protect red[] across calls
    if (lane == 0) red[wave] = x;
    __syncthreads();
    if (threadIdx.x < 64) {
        float y = (threadIdx.x < 16) ? red[threadIdx.x] : 0.f;
        #pragma unroll
        for (int m = 8; m >= 1; m >>= 1) y += __shfl_xor(y, m, 64);
        if (threadIdx.x == 0) red[0] = y;
    }
    __syncthreads();
    return red[0];
}

__global__ __launch_bounds__(1024) void ntm_finalize(
    const float* __restrict__ g_t, const float* __restrict__ s_t,
    const float* __restrict__ gamma_t, const float* __restrict__ w_prev,
    const float* __restrict__ zpartial, float* __restrict__ io)
{
    __shared__ float sh[NN];               // 32 KB: w_g row
    __shared__ float red[16];
    const int b = blockIdx.x;
    const int tid = threadIdx.x;
    const size_t base = (size_t)b * NN;

    const float zl = (tid < 128) ? zpartial[b * 128 + tid] : 0.f;
    const float Z = blockReduceSum(zl, red);

    const float g = g_t[b];
    const float gamma = gamma_t[b];
    const float s0 = s_t[b * 3 + 0], s1 = s_t[b * 3 + 1], s2 = s_t[b * 3 + 2];
    const float gz = g / Z;
    const float omg = 1.f - g;

    #pragma unroll
    for (int k = 0; k < 8; ++k) {
        const int i = tid + k * 1024;
        sh[i] = io[base + i] * gz + omg * w_prev[base + i];   // w_g (>0)
    }
    __syncthreads();

    float wsum = 0.f;
    #pragma unroll
    for (int k = 0; k < 8; ++k) {
        const int i = tid + k * 1024;
        const float wt = s0 * sh[(i + NN - 1) & (NN - 1)]
                       + s1 * sh[i]
                       + s2 * sh[(i + 1) & (NN - 1)];
        wsum += exp2f(gamma * __log2f(wt));            // wt > 0 always
    }
    const float total = blockReduceSum(wsum, red) + OFF;

    #pragma unroll
    for (int k = 0; k < 8; ++k) io[base + tid + k * 1024] = total;
}

// ---------------- launch -----------------------------------------------------
extern "C" void kernel_launch(void* const* d_in, const int* in_sizes, int n_in,
                              void* d_out, int out_size, void* d_ws, size_t ws_size,
                              hipStream_t stream) {
    const float* memory = (const float*)d_in[0];
    const float* k_t    = (const float*)d_in[1];
    const float* beta_t = (const float*)d_in[2];
    const float* g_t    = (const float*)d_in[3];
    const float* s_t    = (const float*)d_in[4];
    const float* gamma_t= (const float*)d_in[5];
    const float* w_prev = (const float*)d_in[6];
    float* out = (float*)d_out;
    float* zpartial = (float*)d_ws;        // B*128 floats, fully rewritten by K1
    const int B = in_sizes[2];             // beta_t element count = 128

    ntm_scores<<<B * 32, 256, 0, stream>>>(memory, k_t, beta_t, out, zpartial);
    ntm_finalize<<<B, 1024, 0, stream>>>(g_t, s_t, gamma_t, w_prev, zpartial, out);
}